// Round 5
// baseline (159.503 us; speedup 1.0000x reference)
//
#include <hip/hip_runtime.h>
#include <math.h>

// RandISH, thread-per-b layout:
//   out[b, 2n+0] = Al(deg_n, r_b) * y0_norm[n] * P_l(ct)
//   out[b, 2n+1] = Al * cs[n] * (-1)^deg * Re[(rx + i*ry)^deg]
// rv = vec[b] @ M[n]; rotation preserves |vec|=1 -> no normalization.
// KEY: with one thread per b, every per-n quantity (deg, mats, coeffs, ...)
// is WAVE-UNIFORM -> scalar loads (SGPRs, no VGPR pressure) and UNIFORM
// branches: the Re[z^d] recurrence runs only deg-1 iterations (deg=1: zero),
// instead of 8 predicated steps per lane.
// Re[z^d]: R_k = 2x R_{k-1} - (x^2+y^2) R_{k-2},  R_0=1, R_1=x.
// Al = exp2(-0.5*d(d+1)*log2e*(r+eps))  (0.5/(1/(r+e)+e) ~= 0.5(r+e), 1e-8 rel).

#define NBASIS 32
#define PLEN 10
#define EPSV 1e-8f
#define LOG2E 1.44269504088896340736f

typedef float f32x4 __attribute__((ext_vector_type(4)));

__global__ __launch_bounds__(256) void randish_kernel(
    const float* __restrict__ vec,        // (B,3)
    const float* __restrict__ rough,      // (B,)
    const float* __restrict__ mats,       // (32,3,3)
    const float* __restrict__ coeffs,     // (32,10) increasing power
    const float* __restrict__ cscale,     // (32,)
    const float* __restrict__ y0n,        // (32,)
    const int*   __restrict__ degs,       // (32,)
    float* __restrict__ out,              // (B,64)
    int B)
{
    const int b = blockIdx.x * blockDim.x + threadIdx.x;
    if (b >= B) return;

    const float v0 = vec[b * 3 + 0];
    const float v1 = vec[b * 3 + 1];
    const float v2 = vec[b * 3 + 2];
    const float te = rough[b] + EPSV;     // (r + eps)

    f32x4* outp = reinterpret_cast<f32x4*>(out + (size_t)b * 2 * NBASIS);

    f32x4 o;
#pragma unroll
    for (int n = 0; n < NBASIS; ++n) {
        const int d   = degs[n];          // wave-uniform -> SGPR
        const int par = d & 1;            // uniform

        // rotate (|rv| == 1); mats[] entries are uniform scalar operands
        const float xh = fmaf(v0, mats[n*9+0], fmaf(v1, mats[n*9+3], v2 * mats[n*9+6]));
        const float yh = fmaf(v0, mats[n*9+1], fmaf(v1, mats[n*9+4], v2 * mats[n*9+7]));
        const float ct = fmaf(v0, mats[n*9+2], fmaf(v1, mats[n*9+5], v2 * mats[n*9+8]));

        // Legendre: P_l(ct) = ct^par * H(ct^2), parity-compressed, zero-padded
        const float ct2 = ct * ct;
        float v = coeffs[n*PLEN + par + 8];
        v = fmaf(v, ct2, coeffs[n*PLEN + par + 6]);
        v = fmaf(v, ct2, coeffs[n*PLEN + par + 4]);
        v = fmaf(v, ct2, coeffs[n*PLEN + par + 2]);
        v = fmaf(v, ct2, coeffs[n*PLEN + par + 0]);
        if (par) v *= ct;                 // uniform branch

        // Re[(xh+i*yh)^d]: uniform-trip-count recurrence (deg=1 -> no work)
        float R = xh;
        if (d > 1) {
            const float ss  = fmaf(yh, yh, xh * xh);
            const float m2x = xh + xh;
            float Rm2 = 1.0f, Rm1 = xh;
            for (int k = 2; k <= d; ++k) {
                const float Rk = fmaf(m2x, Rm1, -(ss * Rm2));
                Rm2 = Rm1;
                Rm1 = Rk;
            }
            R = Rm1;
        }
        float cs = cscale[n];
        if (par) cs = -cs;                // fold (-1)^deg, uniform

        // Al = exp2(negc * (r+eps)), negc uniform
        const float negc = -0.5f * (float)(d * (d + 1)) * LOG2E;
        const float al = __builtin_amdgcn_exp2f(negc * te);

        o[(n & 1) * 2 + 0] = al * (y0n[n] * v);
        o[(n & 1) * 2 + 1] = al * (cs * R);
        if (n & 1)
            __builtin_nontemporal_store(o, outp + (n >> 1));
    }
}

extern "C" void kernel_launch(void* const* d_in, const int* in_sizes, int n_in,
                              void* d_out, int out_size, void* d_ws, size_t ws_size,
                              hipStream_t stream) {
    const float* vec    = (const float*)d_in[0];
    const float* rough  = (const float*)d_in[1];
    const float* mats   = (const float*)d_in[2];
    const float* coeffs = (const float*)d_in[3];
    const float* cscale = (const float*)d_in[4];
    const float* y0n    = (const float*)d_in[5];
    const int*   degs   = (const int*)d_in[6];
    float* out = (float*)d_out;

    const int B = in_sizes[1];            // roughness element count
    const int block = 256;
    const int grid = (B + block - 1) / block;

    randish_kernel<<<grid, block, 0, stream>>>(vec, rough, mats, coeffs, cscale,
                                               y0n, degs, out, B);
}

// Round 6
// 27.098 us; speedup vs baseline: 5.8861x; 5.8861x over previous
//
#include <hip/hip_runtime.h>
#include <math.h>

// RandISH, pair mapping + packed dual-FP32:
//   out[b, 2n+0] = Al(deg_n, r_b) * y0_norm[n] * P_l(ct)
//   out[b, 2n+1] = Al * cscale[n] * (-1)^deg * Re[(rx + i*ry)^deg]
// rv = vec[b] @ M[n]; rotation preserves |vec|=1 -> no normalization.
// Each thread computes bases (n0, n0+1) for one b; the two independent
// slot streams live in the 2 components of f32x2 so the backend emits
// v_pk_fma_f32 / v_pk_mul_f32 (2 FLOPs/inst, the gfx950 fp32 peak rate).
// Re[z^d]: R_k = 2x R_{k-1} - (x^2+y^2) R_{k-2}; all 8 steps computed
// (|R_k|<=1, safe), result picked by mask-FMA with cscale*(-1)^deg folded
// into the mask. Al = exp2(-0.5*d(d+1)*log2e*(r+eps)).

#define NBASIS 32
#define PLEN 10
#define EPSV 1e-8f
#define LOG2E 1.44269504088896340736f

typedef float f32x2 __attribute__((ext_vector_type(2)));
typedef float f32x4 __attribute__((ext_vector_type(4)));

static __device__ __forceinline__ f32x2 fma2(f32x2 a, f32x2 b, f32x2 c) {
    return __builtin_elementwise_fma(a, b, c);
}

__global__ __launch_bounds__(256) void randish_kernel(
    const float* __restrict__ vec,        // (B,3)
    const float* __restrict__ rough,      // (B,)
    const float* __restrict__ mats,       // (32,3,3)
    const float* __restrict__ coeffs,     // (32,10) increasing power
    const float* __restrict__ cscale,     // (32,)
    const float* __restrict__ y0n,        // (32,)
    const int*   __restrict__ degs,       // (32,)
    float* __restrict__ out,              // (B,64)
    int npairs)                           // B*16
{
    const int tid = blockIdx.x * blockDim.x + threadIdx.x;
    const int stride = gridDim.x * blockDim.x;   // multiple of 16 -> n0 invariant
    const int n0 = (2 * tid) & 31;               // slots are bases n0, n0+1

    // ---- loop-invariant per-slot constants, packed slot0/slot1 ----
    f32x2 m[9], h[5], msel[9], maskp, negc2;
    {
        int   dg[2], par[2];
        float cs[2];
#pragma unroll
        for (int s = 0; s < 2; ++s) {
            const int n = n0 + s;
            const int d = degs[n];
            dg[s]  = d;
            par[s] = d & 1;
            float c = cscale[n];
            if (par[s]) c = -c;                  // fold (-1)^deg
            cs[s] = c;
            const float yn = y0n[n];             // fold y0_norm into Horner coeffs
#pragma unroll
            for (int k = 0; k < 5; ++k) {
                const int idx = par[s] + 2 * k;  // parity-compressed Legendre
                const float hv = (idx < PLEN) ? coeffs[n * PLEN + idx] * yn : 0.0f;
                h[k][s] = hv;
            }
#pragma unroll
            for (int j = 0; j < 9; ++j) m[j][s] = mats[n * 9 + j];
            maskp[s] = par[s] ? 1.0f : 0.0f;
            negc2[s] = -0.5f * (float)(d * (d + 1)) * LOG2E;
#pragma unroll
            for (int k = 1; k <= 9; ++k)
                msel[k - 1][s] = (dg[s] == k) ? cs[s] : 0.0f;  // cscale folded in
        }
    }
    const f32x2 one2 = {1.0f, 1.0f};

    for (int p = tid; p < npairs; p += stride) {
        const int b = p >> 4;
        const f32x2 V0 = {vec[b * 3 + 0], vec[b * 3 + 0]};
        const f32x2 V1 = {vec[b * 3 + 1], vec[b * 3 + 1]};
        const f32x2 V2 = {vec[b * 3 + 2], vec[b * 3 + 2]};
        const float te = rough[b] + EPSV;
        const f32x2 te2 = {te, te};

        // rotate (|rv| == 1)
        const f32x2 xh = fma2(V0, m[0], fma2(V1, m[3], V2 * m[6]));
        const f32x2 yh = fma2(V0, m[1], fma2(V1, m[4], V2 * m[7]));
        const f32x2 ct = fma2(V0, m[2], fma2(V1, m[5], V2 * m[8]));

        // Legendre (y0_norm folded): y0 = ct^par * H(ct^2)
        const f32x2 ct2 = ct * ct;
        f32x2 v = h[4];
        v = fma2(v, ct2, h[3]);
        v = fma2(v, ct2, h[2]);
        v = fma2(v, ct2, h[1]);
        v = fma2(v, ct2, h[0]);
        const f32x2 ctp = fma2(maskp, ct - one2, one2);  // par ? ct : 1
        v = v * ctp;

        // cs * Re[(xh+i*yh)^deg] via recurrence + mask-FMA select
        const f32x2 ss  = fma2(yh, yh, xh * xh);
        const f32x2 m2x = xh + xh;
        f32x2 Rm2 = one2;
        f32x2 Rm1 = xh;
        f32x2 res = msel[0] * xh;                 // k = 1
#pragma unroll
        for (int k = 2; k <= 9; ++k) {
            const f32x2 Rk = fma2(m2x, Rm1, -(ss * Rm2));
            res = fma2(msel[k - 1], Rk, res);
            Rm2 = Rm1;
            Rm1 = Rk;
        }

        // Al = exp2(negc * (r+eps)) per slot
        const f32x2 e = negc2 * te2;
        const float al0 = __builtin_amdgcn_exp2f(e[0]);
        const float al1 = __builtin_amdgcn_exp2f(e[1]);

        f32x4 o;
        o[0] = al0 * v[0];
        o[1] = al0 * res[0];
        o[2] = al1 * v[1];
        o[3] = al1 * res[1];
        __builtin_nontemporal_store(o, reinterpret_cast<f32x4*>(out) + p);
    }
}

extern "C" void kernel_launch(void* const* d_in, const int* in_sizes, int n_in,
                              void* d_out, int out_size, void* d_ws, size_t ws_size,
                              hipStream_t stream) {
    const float* vec    = (const float*)d_in[0];
    const float* rough  = (const float*)d_in[1];
    const float* mats   = (const float*)d_in[2];
    const float* coeffs = (const float*)d_in[3];
    const float* cscale = (const float*)d_in[4];
    const float* y0n    = (const float*)d_in[5];
    const int*   degs   = (const int*)d_in[6];
    float* out = (float*)d_out;

    const int B = in_sizes[1];              // roughness element count
    const int npairs = B * (NBASIS / 2);    // one thread per 2 consecutive outputs

    const int block = 256;
    int grid = (npairs + block - 1) / block;
    if (grid > 4096) grid = 4096;           // grid-stride: ~4 pairs/thread

    randish_kernel<<<grid, block, 0, stream>>>(vec, rough, mats, coeffs, cscale,
                                               y0n, degs, out, npairs);
}